// Round 7
// baseline (150.948 us; speedup 1.0000x reference)
//
#include <hip/hip_runtime.h>
#include <stdint.h>

#define HT_STRIDE 262144   // 4096*64 elements per head
#define LOG2E 1.4426950408889634f

typedef __attribute__((ext_vector_type(8))) short bf16x8;
typedef __attribute__((ext_vector_type(4))) float f32x4;
typedef __attribute__((ext_vector_type(2))) float f32x2;

__device__ __forceinline__ unsigned short f2bf(float f) {
    unsigned int u = __float_as_uint(f);
    u += 0x7FFFu + ((u >> 16) & 1u);
    return (unsigned short)(u >> 16);
}

__device__ __forceinline__ float exp2_fast(float e) {
#if __has_builtin(__builtin_amdgcn_exp2f)
    return __builtin_amdgcn_exp2f(e);
#else
    return __expf(e * 0.6931471805599453f);   // expf(ln2*x) == 2^x
#endif
}

// ---------------------------------------------------------------------------
// Kernel 1 (heterogeneous fusion, 1024 blocks x 256 thr):
//  blocks 0..511   : adjacency (64 MB, read once at HBM rate) -> 2 MB bitmask
//                    abm[s64][c 128][li 16][g 4], bit k of word = adj row
//                    (s64*64+16g+li), col (32c+k).
//  blocks 512..1023: linear + prep (ht never touches global). Emits:
//                     - ess: [head][{es,es2}][4096]  es=e^{s}, es2=e^{0.2s}
//                     - ets: [head][{et,et2}][4096]  (SoA -> pk_mul-friendly)
//                       max-of-products identity: exp(lrelu(s+t)) =
//                       max(es*et, es2*et2)  (exp and max commute)
//                     - bf16 k-tiled htT2
// ---------------------------------------------------------------------------
__global__ void __launch_bounds__(256) k_fused(const float* __restrict__ h,
                                               const int* __restrict__ adj,
                                               const float* __restrict__ W,
                                               const float* __restrict__ aW,
                                               float* __restrict__ ess,
                                               float* __restrict__ ets,
                                               unsigned short* __restrict__ htT2,
                                               unsigned int* __restrict__ abm) {
    __shared__ unsigned int ldsT[1024];
    __shared__ float hs[8][128];
    __shared__ float ldsA[64][66];
    __shared__ float redS[4][64];
    __shared__ float redT[4][64];
    const int t = threadIdx.x;

    if (blockIdx.x < 512) {
        // ---------------- adjmask half ----------------
        const int lane = t & 63;
        const int w = t >> 6;
        const int sb = blockIdx.x >> 3;
        const int cq = blockIdx.x & 7;
        for (int rr = 0; rr < 16; ++rr) {
            const int* arow = adj + (sb * 64 + w * 16 + rr) * 4096 + cq * 512;
            int v[8];
            #pragma unroll
            for (int j = 0; j < 8; ++j) v[j] = arow[j * 64 + lane];
            #pragma unroll
            for (int j = 0; j < 8; ++j) {
                unsigned long long m = __ballot(v[j] > 0);
                if (lane < 2)
                    ldsT[(2 * j + lane) * 64 + rr * 4 + w] = (unsigned int)(m >> (lane * 32));
            }
        }
        __syncthreads();
        ((uint4*)(abm + (sb * 128 + cq * 16) * 64))[t] = ((uint4*)ldsT)[t];
    } else {
        // ---------------- linear + prep half ----------------
        const int bid2 = (int)blockIdx.x - 512;
        const int n0 = bid2 * 8;            // P-row base (rows of h @ W)
        const int p0 = bid2 * 64;           // flat node base = hd*4096 + m0
        const int hd = p0 >> 12;
        const int m0 = p0 & 4095;

        // stage 8 h-rows (4 KB), coalesced
        {
            float4 v = ((const float4*)(h + n0 * 128))[t];
            int e = t * 4;
            int r = e >> 7, f = e & 127;
            hs[r][f + 0] = v.x; hs[r][f + 1] = v.y;
            hs[r][f + 2] = v.z; hs[r][f + 3] = v.w;
        }
        __syncthreads();

        // 8x512 P-tile: thread t owns cols (2t, 2t+1) for all 8 rows
        float acc0[8], acc1[8];
        #pragma unroll
        for (int r = 0; r < 8; ++r) { acc0[r] = 0.f; acc1[r] = 0.f; }
        const float2* Wf = (const float2*)W;
        for (int f = 0; f < 128; ++f) {
            float2 wp = Wf[f * 256 + t];
            #pragma unroll
            for (int r = 0; r < 8; ++r) {
                float hv = hs[r][f];
                acc0[r] = fmaf(hv, wp.x, acc0[r]);
                acc1[r] = fmaf(hv, wp.y, acc1[r]);
            }
        }
        // scatter into node-major tile: node = 8r + (2t)>>6, o = (2t)&63
        {
            const int ns = t >> 5;
            const int o = (2 * t) & 63;
            #pragma unroll
            for (int r = 0; r < 8; ++r) {
                *(float2*)&ldsA[r * 8 + ns][o] = make_float2(acc0[r], acc1[r]);
            }
        }
        __syncthreads();

        // src/tgt projections
        {
            const int r = t & 63, og = t >> 6;
            float sdot = 0.f, gdot = 0.f;
            #pragma unroll
            for (int k = 0; k < 16; ++k) {
                int o = og * 16 + k;
                float hv = ldsA[r][o];
                sdot = fmaf(hv, aW[hd * 128 + o], sdot);
                gdot = fmaf(hv, aW[hd * 128 + 64 + o], gdot);
            }
            redS[og][r] = sdot; redT[og][r] = gdot;
        }
        __syncthreads();
        if (t < 64) {
            float sp = (redS[0][t] + redS[1][t] + redS[2][t] + redS[3][t]) * LOG2E;
            ess[hd * 8192 + m0 + t]        = exp2_fast(sp);
            ess[hd * 8192 + 4096 + m0 + t] = exp2_fast(0.2f * sp);
        } else if (t < 128) {
            int r = t - 64;
            float tv = (redT[0][r] + redT[1][r] + redT[2][r] + redT[3][r]) * LOG2E;
            ets[hd * 8192 + m0 + r]        = exp2_fast(tv);
            ets[hd * 8192 + 4096 + m0 + r] = exp2_fast(0.2f * tv);
        }

        // bf16 k-tiled transpose out (reads ldsA, stable since last barrier)
        unsigned short* d = htT2 + (hd * 128 + (m0 >> 5)) * 2048;
        #pragma unroll
        for (int i = 0; i < 16; ++i) {
            int id = t + 256 * i;
            int mi = id & 31, o = (id >> 5) & 63, ct = id >> 11;
            d[ct * 2048 + o * 32 + mi] = f2bf(ldsA[mi + 32 * ct][o]);
        }
    }
}

// ---------------------------------------------------------------------------
// Kernel 2 v9: fused GAT attention, 64-row blocks (A-stream halved + ILP).
// grid 512 x 256: block = (head = bid&7 -> XCD-pinned, s64 = bid>>3).
// 4 waves = 4 k-quarters; wave: 64 rows (4 g2-groups) x 32 c-iters.
// Each c-iter's 4 A-frag loads feed 4 row-groups (~420 issue cyc of work
// per load batch -> single-wave latency self-cover; unroll 2 for cross-iter
// ILP). Per-XCD L2 A-stream: 64 MB -> 32 MB. 2 waves/SIMD, VGPR budget 256.
// Bitmask: one coalesced uint4/lane (native abm g=0..3 layout).
// Mask build: v_bfe_i32 x2 + v_bfi_b32 + v_and (vcc-free, 4 instr/pair).
// LDS: 32 KB et/et2 tables -> comb union 52.2 KB. pd via ones-A MFMA.
// ---------------------------------------------------------------------------
__global__ void __launch_bounds__(256, 2) k_attn(const unsigned int* __restrict__ abm,
                                                 const unsigned short* __restrict__ htT2,
                                                 const float* __restrict__ ess,
                                                 const float* __restrict__ ets,
                                                 float* __restrict__ out) {
    __shared__ __align__(16) float smem[13056];   // 52224 B: et|et2 -> comb union

    const int t = threadIdx.x;
    const int kq = t >> 6;
    const int lane = t & 63;
    const int li = lane & 15;
    const int quad = lane >> 4;
    const int head = blockIdx.x & 7;
    const int s64 = blockIdx.x >> 3;         // 0..63
    const int i0 = s64 * 64;

    // phase 0: stage SoA et/et2 head-slice (32 KB, contiguous copy)
    {
        const float4* esrc = (const float4*)(ets + head * 8192);
        float4* edst = (float4*)smem;
        #pragma unroll
        for (int i = 0; i < 8; ++i) edst[t + 256 * i] = esrc[t + 256 * i];
    }

    // per-row constants (table lookups, no exp): 4 row-groups
    f32x2 esv[4], es2v[4];
    #pragma unroll
    for (int g2 = 0; g2 < 4; ++g2) {
        float e1 = ess[head * 8192 + i0 + 16 * g2 + li];
        float e2 = ess[head * 8192 + 4096 + i0 + 16 * g2 + li];
        esv[g2]  = (f32x2){e1, e1};
        es2v[g2] = (f32x2){e2, e2};
    }

    f32x4 acc[16];
    #pragma unroll
    for (int i = 0; i < 16; ++i) acc[i] = (f32x4){0.f, 0.f, 0.f, 0.f};
    f32x4 apd[4];
    #pragma unroll
    for (int g2 = 0; g2 < 4; ++g2) apd[g2] = (f32x4){0.f, 0.f, 0.f, 0.f};

    const uint4 onesw = {0x3F803F80u, 0x3F803F80u, 0x3F803F80u, 0x3F803F80u};
    const bf16x8 aones = __builtin_bit_cast(bf16x8, onesw);
    const unsigned int lohalf = 0x0000FFFFu;

    const uint4* ap  = (const uint4*)(htT2 + head * HT_STRIDE) + (li * 4 + quad);
    const uint4* bmp = (const uint4*)(abm + s64 * 8192 + li * 4);

    __syncthreads();

    const int c0 = kq * 32;
    #pragma unroll 2
    for (int ci = 0; ci < 32; ++ci) {
        const int c = c0 + ci;
        uint4 av0 = ap[c * 256 + 0];
        uint4 av1 = ap[c * 256 + 64];
        uint4 av2 = ap[c * 256 + 128];
        uint4 av3 = ap[c * 256 + 192];
        uint4 bw = bmp[c * 16];               // g=0..3 bitwords, coalesced

        // SoA et/et2 for this quad's 8 cols (LDS broadcast, pk-adjacent)
        const float4* etp  = (const float4*)(smem + c * 32 + quad * 8);
        const float4* et2p = (const float4*)(smem + 4096 + c * 32 + quad * 8);
        float4 ta = etp[0],  tb = etp[1];
        float4 ua = et2p[0], ub = et2p[1];
        const f32x2 etq[4]  = {(f32x2){ta.x, ta.y}, (f32x2){ta.z, ta.w},
                               (f32x2){tb.x, tb.y}, (f32x2){tb.z, tb.w}};
        const f32x2 et2q[4] = {(f32x2){ua.x, ua.y}, (f32x2){ua.z, ua.w},
                               (f32x2){ub.x, ub.y}, (f32x2){ub.z, ub.w}};

        const unsigned int wb[4] = {bw.x, bw.y, bw.z, bw.w};
        #pragma unroll
        for (int g2 = 0; g2 < 4; ++g2) {
            const unsigned int wq = wb[g2] >> (quad * 8);
            unsigned int pk[4];
            #pragma unroll
            for (int m = 0; m < 4; ++m) {
                f32x2 p1 = etq[m] * esv[g2];          // v_pk_mul_f32
                f32x2 p2 = et2q[m] * es2v[g2];        // v_pk_mul_f32
                float w0 = fmaxf(p1[0], p2[0]);
                float w1 = fmaxf(p1[1], p2[1]);
                unsigned int pkm;
                asm("v_cvt_pk_bf16_f32 %0, %1, %2" : "=v"(pkm) : "v"(w0), "v"(w1));
                // halfword mask from adjacency bits: bfe/bfe/bfi (vcc-free)
                unsigned int lo, hi, msk;
                asm("v_bfe_i32 %0, %1, %2, 1" : "=v"(lo) : "v"(wq), "n"(2 * m));
                asm("v_bfe_i32 %0, %1, %2, 1" : "=v"(hi) : "v"(wq), "n"(2 * m + 1));
                asm("v_bfi_b32 %0, %1, %2, %3" : "=v"(msk) : "v"(lohalf), "v"(lo), "v"(hi));
                pk[m] = pkm & msk;
            }
            uint4 bv; bv.x = pk[0]; bv.y = pk[1]; bv.z = pk[2]; bv.w = pk[3];
            bf16x8 bfrag = __builtin_bit_cast(bf16x8, bv);
            apd[g2] = __builtin_amdgcn_mfma_f32_16x16x32_bf16(aones, bfrag, apd[g2], 0, 0, 0);
            acc[g2 * 4 + 0] = __builtin_amdgcn_mfma_f32_16x16x32_bf16(__builtin_bit_cast(bf16x8, av0), bfrag, acc[g2 * 4 + 0], 0, 0, 0);
            acc[g2 * 4 + 1] = __builtin_amdgcn_mfma_f32_16x16x32_bf16(__builtin_bit_cast(bf16x8, av1), bfrag, acc[g2 * 4 + 1], 0, 0, 0);
            acc[g2 * 4 + 2] = __builtin_amdgcn_mfma_f32_16x16x32_bf16(__builtin_bit_cast(bf16x8, av2), bfrag, acc[g2 * 4 + 2], 0, 0, 0);
            acc[g2 * 4 + 3] = __builtin_amdgcn_mfma_f32_16x16x32_bf16(__builtin_bit_cast(bf16x8, av3), bfrag, acc[g2 * 4 + 3], 0, 0, 0);
        }
    }

    // ---- phase 3: combine 4 k-quarters, denominator, store ----
    __syncthreads();             // all waves done with et tables before overwrite
    if (kq != 0) {
        float* cb = smem + ((kq - 1) * 64 + lane) * 68;  // 272 B stride, 16B-aligned
        #pragma unroll
        for (int i = 0; i < 16; ++i) ((f32x4*)cb)[i] = acc[i];
        #pragma unroll
        for (int g2 = 0; g2 < 4; ++g2) cb[64 + g2] = apd[g2][0];
    }
    __syncthreads();
    if (kq == 0) {
        float pd[4] = {apd[0][0], apd[1][0], apd[2][0], apd[3][0]};
        #pragma unroll
        for (int q = 0; q < 3; ++q) {
            const float* cb = smem + (q * 64 + lane) * 68;
            #pragma unroll
            for (int i = 0; i < 16; ++i) acc[i] += ((const f32x4*)cb)[i];
            #pragma unroll
            for (int g2 = 0; g2 < 4; ++g2) pd[g2] += cb[64 + g2];
        }
        #pragma unroll
        for (int g2 = 0; g2 < 4; ++g2) {
            const float rd = 1.0f / pd[g2];   // ones-MFMA already summed k+quads
            float4* op = (float4*)(out + head * HT_STRIDE + (i0 + 16 * g2 + li) * 64);
            #pragma unroll
            for (int f = 0; f < 4; ++f) {
                f32x4 a = acc[g2 * 4 + f];
                op[f * 4 + quad] = make_float4(a[0] * rd, a[1] * rd, a[2] * rd, a[3] * rd);
            }
        }
    }
}

extern "C" void kernel_launch(void* const* d_in, const int* in_sizes, int n_in,
                              void* d_out, int out_size, void* d_ws, size_t ws_size,
                              hipStream_t stream) {
    const float* h   = (const float*)d_in[0];  // (1,4096,128) f32
    const int*   adj = (const int*)d_in[1];    // (4096,4096) i32
    const float* W   = (const float*)d_in[2];  // (128,512) f32
    const float* aW  = (const float*)d_in[3];  // (8,128,1) f32
    float* out = (float*)d_out;                // (1,8,4096,64) f32

    // ws layout (6.5 MB): ess(256K) | ets(256K) | abm(2MB) | htT2(4MB)
    char* ws = (char*)d_ws;
    float* ess = (float*)(ws);
    float* ets = (float*)(ws + 262144);
    unsigned int*   abm  = (unsigned int*)(ws + 524288);
    unsigned short* htT2 = (unsigned short*)(ws + 2621440);

    hipLaunchKernelGGL(k_fused, dim3(1024), dim3(256), 0, stream,
                       h, adj, W, aW, ess, ets, htT2, abm);
    hipLaunchKernelGGL(k_attn,  dim3(512),  dim3(256), 0, stream,
                       abm, htT2, ess, ets, out);
}